// Round 1
// baseline (510.395 us; speedup 1.0000x reference)
//
#include <hip/hip_runtime.h>
#include <hip/hip_bf16.h>

#define V 50000
#define D 128
#define EF 16
#define E_EDGES 800000
#define NT 12500              // E/64 edge tiles (exact)
#define K1PAD 160             // 144 padded to 5*32
#define XSTR 168              // X LDS row stride (elems): 2-way bank alias only
#define YSTR 136              // Y LDS row stride

typedef __attribute__((ext_vector_type(8))) __bf16 bf16x8;
typedef __attribute__((ext_vector_type(4))) float f32x4;

__device__ inline unsigned short f2bf(float f) {
    unsigned u = __float_as_uint(f);
    u += 0x7FFF + ((u >> 16) & 1);   // RNE
    return (unsigned short)(u >> 16);
}
__device__ inline unsigned pack2(float a, float b) {
    return (unsigned)f2bf(a) | ((unsigned)f2bf(b) << 16);
}

// Repack W1 [144,128] f32 -> bf16 [5][128][32] (k-padded), W2 [128,128] -> [4][128][32].
// Fragment load for (kb, n): 8 contiguous bf16 at ((kb*128+n)*32 + kq*8).
__global__ void pack_weights(const float* __restrict__ W1, const float* __restrict__ W2,
                             unsigned short* __restrict__ W1p, unsigned short* __restrict__ W2p) {
    int idx = blockIdx.x * 256 + threadIdx.x;
    if (idx < 5 * 128 * 32) {
        int kb = idx >> 12;
        int rem = idx & 4095;
        int n = rem >> 5, kk = rem & 31;
        int k = kb * 32 + kk;
        float v = (k < D + EF) ? W1[k * D + n] : 0.0f;
        W1p[idx] = f2bf(v);
    }
    if (idx < 4 * 128 * 32) {
        int kb = idx >> 12;
        int rem = idx & 4095;
        int n = rem >> 5, kk = rem & 31;
        W2p[idx] = f2bf(W2[(kb * 32 + kk) * D + n]);
    }
}

__global__ __launch_bounds__(256, 3)
void edge_kernel(const float* __restrict__ h, const int* __restrict__ ei,
                 const float* __restrict__ ea,
                 const unsigned short* __restrict__ W1p, const unsigned short* __restrict__ W2p,
                 const float* __restrict__ b1, const float* __restrict__ b2,
                 float* __restrict__ agg, float* __restrict__ deg) {
    __shared__ __align__(16) unsigned short Xs[64 * XSTR];
    __shared__ __align__(16) unsigned short Ys[64 * YSTR];
    __shared__ int sSrc[64];
    __shared__ int sDst[64];

    const int tid  = threadIdx.x;
    const int lane = tid & 63;
    const int wave = tid >> 6;      // 0..3, owns N cols [wave*32, wave*32+32)
    const int nlo  = lane & 15;
    const int kq   = lane >> 4;

    // Preload B fragments (persistent across tile loop)
    bf16x8 B1[5][2], B2[4][2];
    float b1v[2], b2v[2];
    #pragma unroll
    for (int t = 0; t < 2; ++t) {
        int n = wave * 32 + t * 16 + nlo;
        b1v[t] = b1[n];
        b2v[t] = b2[n];
        #pragma unroll
        for (int kb = 0; kb < 5; ++kb)
            B1[kb][t] = *(const bf16x8*)(W1p + ((kb << 7) + n) * 32 + (kq << 3));
        #pragma unroll
        for (int kb = 0; kb < 4; ++kb)
            B2[kb][t] = *(const bf16x8*)(W2p + ((kb << 7) + n) * 32 + (kq << 3));
    }

    for (int tile = blockIdx.x; tile < NT; tile += gridDim.x) {
        const int ebase = tile << 6;
        if (tid < 64) {
            int e = ebase + tid;
            sSrc[tid] = ei[e];
            int dn = ei[E_EDGES + e];
            sDst[tid] = dn;
            atomicAdd(&deg[dn], 1.0f);
        }
        __syncthreads();

        // ---- Stage X tile: [64 edges][h(128) | ea(16) | zeros(16)] as bf16 ----
        #pragma unroll
        for (int it = 0; it < 8; ++it) {
            int idx = tid + it * 256;               // 64*32 float4 chunks of h rows
            int e = idx >> 5, c = idx & 31;
            const float4 hv = *(const float4*)(h + (size_t)sSrc[e] * D + (c << 2));
            unsigned* xp = (unsigned*)Xs + e * (XSTR / 2) + (c << 1);
            xp[0] = pack2(hv.x, hv.y);
            xp[1] = pack2(hv.z, hv.w);
        }
        {   // edge_attr: 64 edges * 4 float4 = 256 == blockDim
            int e = tid >> 2, q = tid & 3;
            const float4 av = *(const float4*)(ea + (size_t)(ebase + e) * EF + (q << 2));
            unsigned* xp = (unsigned*)Xs + e * (XSTR / 2) + 64 + (q << 1);
            xp[0] = pack2(av.x, av.y);
            xp[1] = pack2(av.z, av.w);
        }
        {   // zero pad cols 144..159 : 64*8 uints = 512 = 2 per thread
            int i0 = tid, i1 = tid + 256;
            ((unsigned*)Xs)[(i0 >> 3) * (XSTR / 2) + 72 + (i0 & 7)] = 0u;
            ((unsigned*)Xs)[(i1 >> 3) * (XSTR / 2) + 72 + (i1 & 7)] = 0u;
        }
        __syncthreads();

        // ---- Stage 1: C1[64,32cols] = X[64,160] @ W1p ----
        f32x4 acc[4][2];
        #pragma unroll
        for (int mt = 0; mt < 4; ++mt)
            #pragma unroll
            for (int t = 0; t < 2; ++t)
                acc[mt][t] = (f32x4){0.f, 0.f, 0.f, 0.f};

        #pragma unroll
        for (int kb = 0; kb < 5; ++kb) {
            bf16x8 A[4];
            int ko = kb * 32 + (kq << 3);
            #pragma unroll
            for (int mt = 0; mt < 4; ++mt)
                A[mt] = *(const bf16x8*)(Xs + (mt * 16 + nlo) * XSTR + ko);
            #pragma unroll
            for (int mt = 0; mt < 4; ++mt)
                #pragma unroll
                for (int t = 0; t < 2; ++t)
                    acc[mt][t] = __builtin_amdgcn_mfma_f32_16x16x32_bf16(A[mt], B1[kb][t], acc[mt][t], 0, 0, 0);
        }

        // bias + ReLU -> Y (bf16, A-layout source for stage 2)
        #pragma unroll
        for (int mt = 0; mt < 4; ++mt)
            #pragma unroll
            for (int t = 0; t < 2; ++t)
                #pragma unroll
                for (int r = 0; r < 4; ++r) {
                    float v = acc[mt][t][r] + b1v[t];
                    v = fmaxf(v, 0.0f);
                    int row = mt * 16 + (kq << 2) + r;
                    int col = wave * 32 + t * 16 + nlo;
                    Ys[row * YSTR + col] = f2bf(v);
                }
        __syncthreads();

        // ---- Stage 2: C2[64,32cols] = Y[64,128] @ W2p ----
        f32x4 acc2[4][2];
        #pragma unroll
        for (int mt = 0; mt < 4; ++mt)
            #pragma unroll
            for (int t = 0; t < 2; ++t)
                acc2[mt][t] = (f32x4){0.f, 0.f, 0.f, 0.f};

        #pragma unroll
        for (int kb = 0; kb < 4; ++kb) {
            bf16x8 A[4];
            int ko = kb * 32 + (kq << 3);
            #pragma unroll
            for (int mt = 0; mt < 4; ++mt)
                A[mt] = *(const bf16x8*)(Ys + (mt * 16 + nlo) * YSTR + ko);
            #pragma unroll
            for (int mt = 0; mt < 4; ++mt)
                #pragma unroll
                for (int t = 0; t < 2; ++t)
                    acc2[mt][t] = __builtin_amdgcn_mfma_f32_16x16x32_bf16(A[mt], B2[kb][t], acc2[mt][t], 0, 0, 0);
        }

        // epilogue: + b2, scatter-add to agg[dst]
        #pragma unroll
        for (int mt = 0; mt < 4; ++mt)
            #pragma unroll
            for (int t = 0; t < 2; ++t)
                #pragma unroll
                for (int r = 0; r < 4; ++r) {
                    float v = acc2[mt][t][r] + b2v[t];
                    int row = mt * 16 + (kq << 2) + r;
                    int col = wave * 32 + t * 16 + nlo;
                    atomicAdd(&agg[(size_t)sDst[row] * D + col], v);
                }
        __syncthreads();   // protect sSrc/sDst/Xs/Ys before next tile
    }
}

// out = LayerNorm(h + agg/(1+deg)) * gamma + beta ; one wave per node
__global__ __launch_bounds__(256)
void finalize_kernel(const float* __restrict__ h, const float* __restrict__ agg,
                     const float* __restrict__ deg,
                     const float* __restrict__ gamma, const float* __restrict__ beta,
                     float* __restrict__ out) {
    int wave = threadIdx.x >> 6, lane = threadIdx.x & 63;
    int v = blockIdx.x * 4 + wave;
    if (v >= V) return;
    float inv = 1.0f / (1.0f + deg[v]);
    const float* hr = h + (size_t)v * D;
    const float* ar = agg + (size_t)v * D;
    float x0 = hr[lane]      + ar[lane]      * inv;
    float x1 = hr[lane + 64] + ar[lane + 64] * inv;
    float s = x0 + x1;
    #pragma unroll
    for (int m = 32; m; m >>= 1) s += __shfl_xor(s, m);
    float mu = s * (1.0f / 128.0f);
    float d0 = x0 - mu, d1 = x1 - mu;
    float vs = d0 * d0 + d1 * d1;
    #pragma unroll
    for (int m = 32; m; m >>= 1) vs += __shfl_xor(vs, m);
    float rs = rsqrtf(vs * (1.0f / 128.0f) + 1e-5f);
    out[(size_t)v * D + lane]      = d0 * rs * gamma[lane]      + beta[lane];
    out[(size_t)v * D + 64 + lane] = d1 * rs * gamma[lane + 64] + beta[lane + 64];
}

extern "C" void kernel_launch(void* const* d_in, const int* in_sizes, int n_in,
                              void* d_out, int out_size, void* d_ws, size_t ws_size,
                              hipStream_t stream) {
    const float* h     = (const float*)d_in[0];
    const int*   ei    = (const int*)d_in[1];     // [2,E] int32: row0=src, row1=dst
    const float* ea    = (const float*)d_in[2];
    const float* W1    = (const float*)d_in[3];
    const float* b1    = (const float*)d_in[4];
    const float* W2    = (const float*)d_in[5];
    const float* b2    = (const float*)d_in[6];
    const float* gamma = (const float*)d_in[7];
    const float* beta  = (const float*)d_in[8];
    float* out = (float*)d_out;

    char* ws = (char*)d_ws;
    float* agg = (float*)ws;                                  // 25,600,000 B
    float* deg = (float*)(ws + 25600000);                     //    200,000 B
    unsigned short* W1p = (unsigned short*)(ws + 25800000);   //     40,960 B
    unsigned short* W2p = (unsigned short*)(ws + 25840960);   //     32,768 B

    hipMemsetAsync(ws, 0, 25800000, stream);                  // zero agg + deg
    pack_weights<<<80, 256, 0, stream>>>(W1, W2, W1p, W2p);
    edge_kernel<<<2048, 256, 0, stream>>>(h, ei, ea, W1p, W2p, b1, b2, agg, deg);
    finalize_kernel<<<12500, 256, 0, stream>>>(h, agg, deg, gamma, beta, out);
}

// Round 2
// 423.559 us; speedup vs baseline: 1.2050x; 1.2050x over previous
//
#include <hip/hip_runtime.h>
#include <hip/hip_bf16.h>

#define V 50000
#define D 128
#define EF 16
#define E_EDGES 800000
#define NT 12500              // E/64 edge tiles (exact)
#define XSTR 168              // X LDS row stride (ushorts): 336B = 21*16, b128-aligned
#define YSTR 136              // Y LDS row stride (ushorts): 272B = 17*16
#define CSTR 132              // C LDS row stride (floats)

typedef __attribute__((ext_vector_type(8))) __bf16 bf16x8;
typedef __attribute__((ext_vector_type(4))) float f32x4;

__device__ inline unsigned short f2bf(float f) {
    unsigned u = __float_as_uint(f);
    u += 0x7FFF + ((u >> 16) & 1);   // RNE
    return (unsigned short)(u >> 16);
}
__device__ inline unsigned pack2(float a, float b) {
    return (unsigned)f2bf(a) | ((unsigned)f2bf(b) << 16);
}

// ---- one-time packs ----------------------------------------------------

// W1 [144,128] f32 -> bf16 [5][128][32] (k-padded to 160), W2 [128,128] -> [4][128][32]
__global__ void pack_weights(const float* __restrict__ W1, const float* __restrict__ W2,
                             unsigned short* __restrict__ W1p, unsigned short* __restrict__ W2p) {
    int idx = blockIdx.x * 256 + threadIdx.x;
    if (idx < 5 * 128 * 32) {
        int kb = idx >> 12, rem = idx & 4095;
        int n = rem >> 5, kk = rem & 31;
        int k = kb * 32 + kk;
        W1p[idx] = f2bf((k < D + EF) ? W1[k * D + n] : 0.0f);
    }
    if (idx < 4 * 128 * 32) {
        int kb = idx >> 12, rem = idx & 4095;
        int n = rem >> 5, kk = rem & 31;
        W2p[idx] = f2bf(W2[(kb * 32 + kk) * D + n]);
    }
}

// h [V,128] f32 -> bf16 (halves gather bytes in edge kernel)
__global__ void pack_h(const float* __restrict__ h, unsigned short* __restrict__ hbf) {
    int idx = blockIdx.x * 256 + threadIdx.x;          // 1,600,000 float4 chunks exact
    const float4 v = *(const float4*)(h + ((size_t)idx << 2));
    unsigned* o = (unsigned*)hbf + (idx << 1);
    o[0] = pack2(v.x, v.y);
    o[1] = pack2(v.z, v.w);
}

// ---- counting sort of edges by dst ------------------------------------

__global__ void hist_kernel(const int* __restrict__ ei, int* __restrict__ cnt) {
    int e = blockIdx.x * 256 + threadIdx.x;            // 3125*256 = E exact
    atomicAdd(&cnt[ei[E_EDGES + e]], 1);
}

__global__ __launch_bounds__(1024)
void scan_kernel(const int* __restrict__ cnt, int* __restrict__ cursor) {
    __shared__ int wsum[16];
    const int t = threadIdx.x;
    const int lo = t * 49;                              // 1024*49 = 50176 >= V
    const int hi = min(lo + 49, V);
    int s = 0;
    for (int v = lo; v < hi; ++v) s += cnt[v];
    const int lane = t & 63, w = t >> 6;
    int x = s;
    #pragma unroll
    for (int off = 1; off < 64; off <<= 1) {
        int y = __shfl_up(x, off);
        if (lane >= off) x += y;
    }
    if (lane == 63) wsum[w] = x;
    __syncthreads();
    if (t == 0) {
        int run = 0;
        #pragma unroll
        for (int i = 0; i < 16; ++i) { int c = wsum[i]; wsum[i] = run; run += c; }
    }
    __syncthreads();
    int base = wsum[w] + (x - s);                       // exclusive prefix for this thread
    for (int v = lo; v < hi; ++v) { cursor[v] = base; base += cnt[v]; }
}

__global__ void scatter_kernel(const int* __restrict__ ei, int* __restrict__ cursor,
                               int* __restrict__ perm) {
    int e = blockIdx.x * 256 + threadIdx.x;            // 3125*256 = E exact
    int d = ei[E_EDGES + e];
    int pos = atomicAdd(&cursor[d], 1);
    perm[pos] = e;
}

// ---- edge MLP + segmented scatter -------------------------------------

__global__ __launch_bounds__(256, 3)
void edge_kernel(const unsigned short* __restrict__ hbf, const int* __restrict__ ei,
                 const float* __restrict__ ea, const int* __restrict__ perm,
                 const unsigned short* __restrict__ W1p, const unsigned short* __restrict__ W2p,
                 const float* __restrict__ b1, const float* __restrict__ b2,
                 float* __restrict__ agg) {
    union SharedU {
        struct { unsigned short Xs[64 * XSTR]; unsigned short Ys[64 * YSTR]; } s; // 38,912 B
        float C[64 * CSTR];                                                        // 33,792 B
    };
    __shared__ __align__(16) SharedU u;
    __shared__ int sSrc[64];
    __shared__ int sDst[64];
    __shared__ int sE[64];

    const int tid  = threadIdx.x;
    const int lane = tid & 63;
    const int wave = tid >> 6;      // 0..3, owns N cols [wave*32, wave*32+32)
    const int nlo  = lane & 15;
    const int kq   = lane >> 4;

    // Persistent B fragments
    bf16x8 B1[5][2], B2[4][2];
    float b1v[2], b2v[2];
    #pragma unroll
    for (int t = 0; t < 2; ++t) {
        int n = wave * 32 + t * 16 + nlo;
        b1v[t] = b1[n];
        b2v[t] = b2[n];
        #pragma unroll
        for (int kb = 0; kb < 5; ++kb)
            B1[kb][t] = *(const bf16x8*)(W1p + ((kb << 7) + n) * 32 + (kq << 3));
        #pragma unroll
        for (int kb = 0; kb < 4; ++kb)
            B2[kb][t] = *(const bf16x8*)(W2p + ((kb << 7) + n) * 32 + (kq << 3));
    }

    for (int tile = blockIdx.x; tile < NT; tile += gridDim.x) {
        const int ebase = tile << 6;
        if (tid < 64) {
            int e = perm[ebase + tid];
            sE[tid] = e;
            sSrc[tid] = ei[e];
            sDst[tid] = ei[E_EDGES + e];    // non-decreasing within + across tiles
        }
        __syncthreads();

        // ---- Stage X tile: [64 edges][hbf(128) | ea->bf16(16) | zeros(16)] ----
        #pragma unroll
        for (int it = 0; it < 4; ++it) {
            int idx = tid + it * 256;              // 64 rows * 16 bf16x8 chunks
            int e = idx >> 4, c = idx & 15;
            const bf16x8 hv = *(const bf16x8*)(hbf + (size_t)sSrc[e] * D + (c << 3));
            *(bf16x8*)(u.s.Xs + e * XSTR + (c << 3)) = hv;
        }
        {   // edge_attr: 64 edges * 4 float4 = 256
            int e = tid >> 2, q = tid & 3;
            const float4 av = *(const float4*)(ea + (size_t)sE[e] * EF + (q << 2));
            unsigned* xp = (unsigned*)(u.s.Xs) + e * (XSTR / 2) + 64 + (q << 1);
            xp[0] = pack2(av.x, av.y);
            xp[1] = pack2(av.z, av.w);
        }
        {   // zero pad k = 144..159
            int i0 = tid, i1 = tid + 256;
            ((unsigned*)(u.s.Xs))[(i0 >> 3) * (XSTR / 2) + 72 + (i0 & 7)] = 0u;
            ((unsigned*)(u.s.Xs))[(i1 >> 3) * (XSTR / 2) + 72 + (i1 & 7)] = 0u;
        }
        __syncthreads();

        // ---- Stage 1: X[64,160] @ W1 ----
        f32x4 acc[4][2];
        #pragma unroll
        for (int mt = 0; mt < 4; ++mt)
            #pragma unroll
            for (int t = 0; t < 2; ++t)
                acc[mt][t] = (f32x4){0.f, 0.f, 0.f, 0.f};

        #pragma unroll
        for (int kb = 0; kb < 5; ++kb) {
            bf16x8 A[4];
            int ko = kb * 32 + (kq << 3);
            #pragma unroll
            for (int mt = 0; mt < 4; ++mt)
                A[mt] = *(const bf16x8*)(u.s.Xs + (mt * 16 + nlo) * XSTR + ko);
            #pragma unroll
            for (int mt = 0; mt < 4; ++mt)
                #pragma unroll
                for (int t = 0; t < 2; ++t)
                    acc[mt][t] = __builtin_amdgcn_mfma_f32_16x16x32_bf16(A[mt], B1[kb][t], acc[mt][t], 0, 0, 0);
        }

        // bias + ReLU -> Ys (bf16)
        #pragma unroll
        for (int mt = 0; mt < 4; ++mt)
            #pragma unroll
            for (int t = 0; t < 2; ++t)
                #pragma unroll
                for (int r = 0; r < 4; ++r) {
                    float v = fmaxf(acc[mt][t][r] + b1v[t], 0.0f);
                    int row = mt * 16 + (kq << 2) + r;
                    int col = wave * 32 + t * 16 + nlo;
                    u.s.Ys[row * YSTR + col] = f2bf(v);
                }
        __syncthreads();

        // ---- Stage 2: Y[64,128] @ W2 ----
        f32x4 acc2[4][2];
        #pragma unroll
        for (int mt = 0; mt < 4; ++mt)
            #pragma unroll
            for (int t = 0; t < 2; ++t)
                acc2[mt][t] = (f32x4){0.f, 0.f, 0.f, 0.f};

        #pragma unroll
        for (int kb = 0; kb < 4; ++kb) {
            bf16x8 A[4];
            int ko = kb * 32 + (kq << 3);
            #pragma unroll
            for (int mt = 0; mt < 4; ++mt)
                A[mt] = *(const bf16x8*)(u.s.Ys + (mt * 16 + nlo) * YSTR + ko);
            #pragma unroll
            for (int mt = 0; mt < 4; ++mt)
                #pragma unroll
                for (int t = 0; t < 2; ++t)
                    acc2[mt][t] = __builtin_amdgcn_mfma_f32_16x16x32_bf16(A[mt], B2[kb][t], acc2[mt][t], 0, 0, 0);
        }
        __syncthreads();    // all Ys reads done before C overwrites the union

        // C = acc2 + b2 -> LDS (f32, [row][col], stride 132)
        #pragma unroll
        for (int mt = 0; mt < 4; ++mt)
            #pragma unroll
            for (int t = 0; t < 2; ++t)
                #pragma unroll
                for (int r = 0; r < 4; ++r) {
                    int row = mt * 16 + (kq << 2) + r;
                    int col = wave * 32 + t * 16 + nlo;
                    u.C[row * CSTR + col] = acc2[mt][t][r] + b2v[t];
                }
        __syncthreads();

        // segmented run-reduction over sorted dst: ~1 atomic per (run, col)
        {
            int col = tid & 127;
            int rbase = (tid >> 7) << 5;            // rows [rbase, rbase+32)
            float sum = 0.f;
            int cur = sDst[rbase];
            for (int i = 0; i < 32; ++i) {
                int row = rbase + i;
                int d = sDst[row];                  // wave-uniform broadcast
                if (d != cur) {
                    atomicAdd(&agg[(size_t)cur * D + col], sum);
                    sum = 0.f;
                    cur = d;
                }
                sum += u.C[row * CSTR + col];
            }
            atomicAdd(&agg[(size_t)cur * D + col], sum);
        }
        __syncthreads();    // scans done before next tile's staging
    }
}

// out = LayerNorm(h + agg/(1+deg)) * gamma + beta ; one wave per node
__global__ __launch_bounds__(256)
void finalize_kernel(const float* __restrict__ h, const float* __restrict__ agg,
                     const int* __restrict__ cnt,
                     const float* __restrict__ gamma, const float* __restrict__ beta,
                     float* __restrict__ out) {
    int wave = threadIdx.x >> 6, lane = threadIdx.x & 63;
    int v = blockIdx.x * 4 + wave;
    if (v >= V) return;
    float inv = 1.0f / (1.0f + (float)cnt[v]);
    const float* hr = h + (size_t)v * D;
    const float* ar = agg + (size_t)v * D;
    float x0 = hr[lane]      + ar[lane]      * inv;
    float x1 = hr[lane + 64] + ar[lane + 64] * inv;
    float s = x0 + x1;
    #pragma unroll
    for (int m = 32; m; m >>= 1) s += __shfl_xor(s, m);
    float mu = s * (1.0f / 128.0f);
    float d0 = x0 - mu, d1 = x1 - mu;
    float vs = d0 * d0 + d1 * d1;
    #pragma unroll
    for (int m = 32; m; m >>= 1) vs += __shfl_xor(vs, m);
    float rs = rsqrtf(vs * (1.0f / 128.0f) + 1e-5f);
    out[(size_t)v * D + lane]      = d0 * rs * gamma[lane]      + beta[lane];
    out[(size_t)v * D + 64 + lane] = d1 * rs * gamma[lane + 64] + beta[lane + 64];
}

extern "C" void kernel_launch(void* const* d_in, const int* in_sizes, int n_in,
                              void* d_out, int out_size, void* d_ws, size_t ws_size,
                              hipStream_t stream) {
    const float* h     = (const float*)d_in[0];
    const int*   ei    = (const int*)d_in[1];     // [2,E]: row0=src, row1=dst
    const float* ea    = (const float*)d_in[2];
    const float* W1    = (const float*)d_in[3];
    const float* b1    = (const float*)d_in[4];
    const float* W2    = (const float*)d_in[5];
    const float* b2    = (const float*)d_in[6];
    const float* gamma = (const float*)d_in[7];
    const float* beta  = (const float*)d_in[8];
    float* out = (float*)d_out;

    char* ws = (char*)d_ws;
    float*          agg    = (float*)ws;                          // 25,600,000
    int*            cnt    = (int*)(ws + 25600000);               //    200,000 (also deg)
    int*            cursor = (int*)(ws + 25800000);               //    200,000
    int*            perm   = (int*)(ws + 26000000);               //  3,200,000
    unsigned short* W1p    = (unsigned short*)(ws + 29200000);    //     40,960
    unsigned short* W2p    = (unsigned short*)(ws + 29240960);    //     32,768
    unsigned short* hbf    = (unsigned short*)(ws + 29273728);    // 12,800,000  (tot ~42.1 MB)

    hipMemsetAsync(ws, 0, 25800000, stream);                      // agg + cnt
    pack_weights<<<80, 256, 0, stream>>>(W1, W2, W1p, W2p);
    pack_h<<<6250, 256, 0, stream>>>(h, hbf);
    hist_kernel<<<3125, 256, 0, stream>>>(ei, cnt);
    scan_kernel<<<1, 1024, 0, stream>>>(cnt, cursor);
    scatter_kernel<<<3125, 256, 0, stream>>>(ei, cursor, perm);
    edge_kernel<<<2048, 256, 0, stream>>>(hbf, ei, ea, perm, W1p, W2p, b1, b2, agg);
    finalize_kernel<<<12500, 256, 0, stream>>>(h, agg, cnt, gamma, beta, out);
}

// Round 3
// 404.253 us; speedup vs baseline: 1.2626x; 1.0478x over previous
//
#include <hip/hip_runtime.h>
#include <hip/hip_bf16.h>

#define V 50000
#define D 128
#define EF 16
#define E_EDGES 800000
#define NT 12500              // E/64 edge tiles (exact)
#define XSTR 168              // X LDS row stride (ushorts): 336B, b128-aligned
#define YSTR 136              // Y LDS row stride (ushorts): 272B
#define CSTR 132              // C LDS row stride (floats)
#define NSCAN 196             // ceil(V/256)

typedef __attribute__((ext_vector_type(8))) __bf16 bf16x8;
typedef __attribute__((ext_vector_type(4))) float f32x4;

__device__ inline unsigned short f2bf(float f) {
    unsigned u = __float_as_uint(f);
    u += 0x7FFF + ((u >> 16) & 1);   // RNE
    return (unsigned short)(u >> 16);
}
__device__ inline unsigned pack2(float a, float b) {
    return (unsigned)f2bf(a) | ((unsigned)f2bf(b) << 16);
}

// ---- one-time packs ----------------------------------------------------

// W1 [144,128] f32 -> bf16 [5][128][32] (k-padded to 160), W2 [128,128] -> [4][128][32]
__global__ void pack_weights(const float* __restrict__ W1, const float* __restrict__ W2,
                             unsigned short* __restrict__ W1p, unsigned short* __restrict__ W2p) {
    int idx = blockIdx.x * 256 + threadIdx.x;
    if (idx < 5 * 128 * 32) {
        int kb = idx >> 12, rem = idx & 4095;
        int n = rem >> 5, kk = rem & 31;
        int k = kb * 32 + kk;
        W1p[idx] = f2bf((k < D + EF) ? W1[k * D + n] : 0.0f);
    }
    if (idx < 4 * 128 * 32) {
        int kb = idx >> 12, rem = idx & 4095;
        int n = rem >> 5, kk = rem & 31;
        W2p[idx] = f2bf(W2[(kb * 32 + kk) * D + n]);
    }
}

// h [V,128] f32 -> bf16; fused dst-histogram (first 800K threads)
__global__ void pack_h_hist(const float* __restrict__ h, unsigned short* __restrict__ hbf,
                            const int* __restrict__ ei, int* __restrict__ cnt) {
    int idx = blockIdx.x * 256 + threadIdx.x;          // 1,600,000 float4 chunks exact
    const float4 v = *(const float4*)(h + ((size_t)idx << 2));
    unsigned* o = (unsigned*)hbf + (idx << 1);
    o[0] = pack2(v.x, v.y);
    o[1] = pack2(v.z, v.w);
    if (idx < E_EDGES) atomicAdd(&cnt[ei[E_EDGES + idx]], 1);
}

// ---- counting sort of edges by dst (parallel 2-level scan) ------------

__device__ inline int block_excl_scan(int x, int t, int* ws, int* total) {
    int lane = t & 63, w = t >> 6;
    int inc = x;
    #pragma unroll
    for (int off = 1; off < 64; off <<= 1) {
        int y = __shfl_up(inc, off);
        if (lane >= off) inc += y;
    }
    if (lane == 63) ws[w] = inc;
    __syncthreads();
    if (t == 0) {
        int r = 0;
        #pragma unroll
        for (int i = 0; i < 4; ++i) { int c = ws[i]; ws[i] = r; r += c; }
        ws[4] = r;                               // block total
    }
    __syncthreads();
    *total = ws[4];
    return inc - x + ws[w];
}

__global__ __launch_bounds__(256)
void scan1_kernel(const int* __restrict__ cnt, int* __restrict__ cursor,
                  int* __restrict__ bsum) {
    __shared__ int ws[5];
    int t = threadIdx.x;
    int i = blockIdx.x * 256 + t;
    int x = (i < V) ? cnt[i] : 0;
    int total;
    int ex = block_excl_scan(x, t, ws, &total);
    if (i < V) cursor[i] = ex;
    if (t == 0) bsum[blockIdx.x] = total;
}

__global__ __launch_bounds__(256)
void scan2_kernel(const int* __restrict__ bsum, int* __restrict__ boff) {
    __shared__ int ws[5];
    int t = threadIdx.x;
    int x = (t < NSCAN) ? bsum[t] : 0;
    int total;
    int ex = block_excl_scan(x, t, ws, &total);
    if (t < NSCAN) boff[t] = ex;
}

__global__ void scatter_kernel(const int* __restrict__ ei, int* __restrict__ cursor,
                               const int* __restrict__ boff, int* __restrict__ perm) {
    int e = blockIdx.x * 256 + threadIdx.x;            // 3125*256 = E exact
    int d = ei[E_EDGES + e];
    int pos = atomicAdd(&cursor[d], 1) + boff[d >> 8];
    perm[pos] = e;
}

// ---- edge MLP + segmented scatter -------------------------------------

__global__ __launch_bounds__(256, 4)
void edge_kernel(const unsigned short* __restrict__ hbf, const int* __restrict__ ei,
                 const float* __restrict__ ea, const int* __restrict__ perm,
                 const unsigned short* __restrict__ W1p, const unsigned short* __restrict__ W2p,
                 const float* __restrict__ b1, const float* __restrict__ b2,
                 float* __restrict__ agg) {
    union SharedU {
        struct { unsigned short Xs[64 * XSTR]; unsigned short Ys[64 * YSTR]; } s; // 38,912 B
        float C[64 * CSTR];                                                        // 33,792 B
    };
    __shared__ __align__(16) SharedU u;
    __shared__ int sSrc[64];
    __shared__ int sDst[64];
    __shared__ int sE[64];

    const int tid  = threadIdx.x;
    const int lane = tid & 63;
    const int wave = tid >> 6;      // 0..3, owns N cols [wave*32, wave*32+32)
    const int nlo  = lane & 15;
    const int kq   = lane >> 4;

    // Persistent B fragments
    bf16x8 B1[5][2], B2[4][2];
    float b1v[2], b2v[2];
    #pragma unroll
    for (int t = 0; t < 2; ++t) {
        int n = wave * 32 + t * 16 + nlo;
        b1v[t] = b1[n];
        b2v[t] = b2[n];
        #pragma unroll
        for (int kb = 0; kb < 5; ++kb)
            B1[kb][t] = *(const bf16x8*)(W1p + ((kb << 7) + n) * 32 + (kq << 3));
        #pragma unroll
        for (int kb = 0; kb < 4; ++kb)
            B2[kb][t] = *(const bf16x8*)(W2p + ((kb << 7) + n) * 32 + (kq << 3));
    }

    for (int tile = blockIdx.x; tile < NT; tile += gridDim.x) {
        const int ebase = tile << 6;
        if (tid < 64) {
            int e = perm[ebase + tid];
            sE[tid] = e;
            sSrc[tid] = ei[e];
            sDst[tid] = ei[E_EDGES + e];    // non-decreasing across sorted order
        }
        __syncthreads();

        // ---- Stage X tile: [64 edges][hbf(128) | ea->bf16(16) | zeros(16)] ----
        #pragma unroll
        for (int it = 0; it < 4; ++it) {
            int idx = tid + it * 256;              // 64 rows * 16 bf16x8 chunks
            int e = idx >> 4, c = idx & 15;
            const bf16x8 hv = *(const bf16x8*)(hbf + (size_t)sSrc[e] * D + (c << 3));
            *(bf16x8*)(u.s.Xs + e * XSTR + (c << 3)) = hv;
        }
        {   // edge_attr: 64 edges * 4 float4 = 256
            int e = tid >> 2, q = tid & 3;
            const float4 av = *(const float4*)(ea + (size_t)sE[e] * EF + (q << 2));
            unsigned* xp = (unsigned*)(u.s.Xs) + e * (XSTR / 2) + 64 + (q << 1);
            xp[0] = pack2(av.x, av.y);
            xp[1] = pack2(av.z, av.w);
        }
        {   // zero pad k = 144..159
            int i0 = tid, i1 = tid + 256;
            ((unsigned*)(u.s.Xs))[(i0 >> 3) * (XSTR / 2) + 72 + (i0 & 7)] = 0u;
            ((unsigned*)(u.s.Xs))[(i1 >> 3) * (XSTR / 2) + 72 + (i1 & 7)] = 0u;
        }
        __syncthreads();

        // ---- Stage 1: X[64,160] @ W1 ----
        f32x4 acc[4][2];
        #pragma unroll
        for (int mt = 0; mt < 4; ++mt)
            #pragma unroll
            for (int t = 0; t < 2; ++t)
                acc[mt][t] = (f32x4){0.f, 0.f, 0.f, 0.f};

        #pragma unroll
        for (int kb = 0; kb < 5; ++kb) {
            bf16x8 A[4];
            int ko = kb * 32 + (kq << 3);
            #pragma unroll
            for (int mt = 0; mt < 4; ++mt)
                A[mt] = *(const bf16x8*)(u.s.Xs + (mt * 16 + nlo) * XSTR + ko);
            #pragma unroll
            for (int mt = 0; mt < 4; ++mt)
                #pragma unroll
                for (int t = 0; t < 2; ++t)
                    acc[mt][t] = __builtin_amdgcn_mfma_f32_16x16x32_bf16(A[mt], B1[kb][t], acc[mt][t], 0, 0, 0);
        }

        // bias + ReLU -> Ys (bf16)
        #pragma unroll
        for (int mt = 0; mt < 4; ++mt)
            #pragma unroll
            for (int t = 0; t < 2; ++t)
                #pragma unroll
                for (int r = 0; r < 4; ++r) {
                    float v = fmaxf(acc[mt][t][r] + b1v[t], 0.0f);
                    int row = mt * 16 + (kq << 2) + r;
                    int col = wave * 32 + t * 16 + nlo;
                    u.s.Ys[row * YSTR + col] = f2bf(v);
                }
        __syncthreads();

        // ---- Stage 2: Y[64,128] @ W2 ----
        f32x4 acc2[4][2];
        #pragma unroll
        for (int mt = 0; mt < 4; ++mt)
            #pragma unroll
            for (int t = 0; t < 2; ++t)
                acc2[mt][t] = (f32x4){0.f, 0.f, 0.f, 0.f};

        #pragma unroll
        for (int kb = 0; kb < 4; ++kb) {
            bf16x8 A[4];
            int ko = kb * 32 + (kq << 3);
            #pragma unroll
            for (int mt = 0; mt < 4; ++mt)
                A[mt] = *(const bf16x8*)(u.s.Ys + (mt * 16 + nlo) * YSTR + ko);
            #pragma unroll
            for (int mt = 0; mt < 4; ++mt)
                #pragma unroll
                for (int t = 0; t < 2; ++t)
                    acc2[mt][t] = __builtin_amdgcn_mfma_f32_16x16x32_bf16(A[mt], B2[kb][t], acc2[mt][t], 0, 0, 0);
        }
        __syncthreads();    // all Ys reads done before C overwrites the union

        // C = acc2 + b2 -> LDS (f32, [row][col], stride 132)
        #pragma unroll
        for (int mt = 0; mt < 4; ++mt)
            #pragma unroll
            for (int t = 0; t < 2; ++t)
                #pragma unroll
                for (int r = 0; r < 4; ++r) {
                    int row = mt * 16 + (kq << 2) + r;
                    int col = wave * 32 + t * 16 + nlo;
                    u.C[row * CSTR + col] = acc2[mt][t][r] + b2v[t];
                }
        __syncthreads();

        // segmented run-reduction over sorted dst: ~1 atomic per (run, col)
        {
            int col = tid & 127;
            int rbase = (tid >> 7) << 5;            // rows [rbase, rbase+32)
            float sum = 0.f;
            int cur = sDst[rbase];
            for (int i = 0; i < 32; ++i) {
                int row = rbase + i;
                int d = sDst[row];                  // wave-uniform broadcast
                if (d != cur) {
                    atomicAdd(&agg[(size_t)cur * D + col], sum);
                    sum = 0.f;
                    cur = d;
                }
                sum += u.C[row * CSTR + col];
            }
            atomicAdd(&agg[(size_t)cur * D + col], sum);
        }
        __syncthreads();    // scans done before next tile's staging
    }
}

// out = LayerNorm(h + agg/(1+deg)) * gamma + beta ; one wave per node
__global__ __launch_bounds__(256)
void finalize_kernel(const float* __restrict__ h, const float* __restrict__ agg,
                     const int* __restrict__ cnt,
                     const float* __restrict__ gamma, const float* __restrict__ beta,
                     float* __restrict__ out) {
    int wave = threadIdx.x >> 6, lane = threadIdx.x & 63;
    int v = blockIdx.x * 4 + wave;
    if (v >= V) return;
    float inv = 1.0f / (1.0f + (float)cnt[v]);
    const float* hr = h + (size_t)v * D;
    const float* ar = agg + (size_t)v * D;
    float x0 = hr[lane]      + ar[lane]      * inv;
    float x1 = hr[lane + 64] + ar[lane + 64] * inv;
    float s = x0 + x1;
    #pragma unroll
    for (int m = 32; m; m >>= 1) s += __shfl_xor(s, m);
    float mu = s * (1.0f / 128.0f);
    float d0 = x0 - mu, d1 = x1 - mu;
    float vs = d0 * d0 + d1 * d1;
    #pragma unroll
    for (int m = 32; m; m >>= 1) vs += __shfl_xor(vs, m);
    float rs = rsqrtf(vs * (1.0f / 128.0f) + 1e-5f);
    out[(size_t)v * D + lane]      = d0 * rs * gamma[lane]      + beta[lane];
    out[(size_t)v * D + 64 + lane] = d1 * rs * gamma[lane + 64] + beta[lane + 64];
}

extern "C" void kernel_launch(void* const* d_in, const int* in_sizes, int n_in,
                              void* d_out, int out_size, void* d_ws, size_t ws_size,
                              hipStream_t stream) {
    const float* h     = (const float*)d_in[0];
    const int*   ei    = (const int*)d_in[1];     // [2,E]: row0=src, row1=dst
    const float* ea    = (const float*)d_in[2];
    const float* W1    = (const float*)d_in[3];
    const float* b1    = (const float*)d_in[4];
    const float* W2    = (const float*)d_in[5];
    const float* b2    = (const float*)d_in[6];
    const float* gamma = (const float*)d_in[7];
    const float* beta  = (const float*)d_in[8];
    float* out = (float*)d_out;

    char* ws = (char*)d_ws;
    float*          agg    = (float*)ws;                          // 25,600,000
    int*            cnt    = (int*)(ws + 25600000);               //    200,000 (also deg)
    int*            cursor = (int*)(ws + 25800000);               //    200,000
    int*            bsum   = (int*)(ws + 26000000);               //        784 -> pad 800
    int*            boff   = (int*)(ws + 26000800);               //        784 -> pad 800
    int*            perm   = (int*)(ws + 26001600);               //  3,200,000
    unsigned short* W1p    = (unsigned short*)(ws + 29201600);    //     40,960
    unsigned short* W2p    = (unsigned short*)(ws + 29242560);    //     32,768
    unsigned short* hbf    = (unsigned short*)(ws + 29275328);    // 12,800,000 (tot ~42.1 MB)

    hipMemsetAsync(ws, 0, 25800000, stream);                      // agg + cnt
    pack_weights<<<80, 256, 0, stream>>>(W1, W2, W1p, W2p);
    pack_h_hist<<<6250, 256, 0, stream>>>(h, hbf, ei, cnt);
    scan1_kernel<<<NSCAN, 256, 0, stream>>>(cnt, cursor, bsum);
    scan2_kernel<<<1, 256, 0, stream>>>(bsum, boff);
    scatter_kernel<<<3125, 256, 0, stream>>>(ei, cursor, boff, perm);
    edge_kernel<<<2048, 256, 0, stream>>>(hbf, ei, ea, perm, W1p, W2p, b1, b2, agg);
    finalize_kernel<<<12500, 256, 0, stream>>>(h, agg, cnt, gamma, beta, out);
}

// Round 4
// 381.336 us; speedup vs baseline: 1.3384x; 1.0601x over previous
//
#include <hip/hip_runtime.h>
#include <hip/hip_bf16.h>

#define V 50000
#define D 128
#define EF 16
#define E_EDGES 800000
#define NT 12500              // E/64 edge tiles (exact)
#define XSTR 168              // X LDS row stride (ushorts): 336B, b128-aligned
#define YSTR 136              // Y LDS row stride (ushorts): 272B
#define CSTR 132              // C LDS row stride (floats)
#define NSCAN 196             // ceil(V/256)
#define EGRID 1024

typedef __attribute__((ext_vector_type(8))) __bf16 bf16x8;
typedef __attribute__((ext_vector_type(4))) float f32x4;

__device__ inline unsigned short f2bf(float f) {
    unsigned u = __float_as_uint(f);
    u += 0x7FFF + ((u >> 16) & 1);   // RNE
    return (unsigned short)(u >> 16);
}
__device__ inline unsigned pack2(float a, float b) {
    return (unsigned)f2bf(a) | ((unsigned)f2bf(b) << 16);
}

// ---- setup: zero agg + pack h->bf16 + dst histogram + pack weights ----
__global__ __launch_bounds__(256)
void setup_kernel(const float* __restrict__ h, unsigned short* __restrict__ hbf,
                  const int* __restrict__ ei, int* __restrict__ cnt,
                  float* __restrict__ agg,
                  const float* __restrict__ W1, const float* __restrict__ W2,
                  unsigned short* __restrict__ W1p, unsigned short* __restrict__ W2p) {
    int idx = blockIdx.x * 256 + threadIdx.x;          // 1,600,000 exact
    const float4 v = *(const float4*)(h + ((size_t)idx << 2));
    unsigned* o = (unsigned*)hbf + (idx << 1);
    o[0] = pack2(v.x, v.y);
    o[1] = pack2(v.z, v.w);
    *(float4*)(agg + ((size_t)idx << 2)) = (float4){0.f, 0.f, 0.f, 0.f};
    if (idx < E_EDGES) atomicAdd(&cnt[ei[E_EDGES + idx]], 1);
    if (idx < 5 * 128 * 32) {
        int kb = idx >> 12, rem = idx & 4095;
        int n = rem >> 5, kk = rem & 31;
        int k = kb * 32 + kk;
        W1p[idx] = f2bf((k < D + EF) ? W1[k * D + n] : 0.0f);
    }
    if (idx < 4 * 128 * 32) {
        int kb = idx >> 12, rem = idx & 4095;
        int n = rem >> 5, kk = rem & 31;
        W2p[idx] = f2bf(W2[(kb * 32 + kk) * D + n]);
    }
}

// ---- counting sort ----------------------------------------------------
__device__ inline int block_excl_scan(int x, int t, int* ws) {
    int lane = t & 63, w = t >> 6;
    int inc = x;
    #pragma unroll
    for (int off = 1; off < 64; off <<= 1) {
        int y = __shfl_up(inc, off);
        if (lane >= off) inc += y;
    }
    if (lane == 63) ws[w] = inc;
    __syncthreads();
    if (t == 0) {
        int r = 0;
        #pragma unroll
        for (int i = 0; i < 4; ++i) { int c = ws[i]; ws[i] = r; r += c; }
    }
    __syncthreads();
    return inc - x + ws[w];
}

__global__ __launch_bounds__(256)
void scan1_kernel(const int* __restrict__ cnt, int* __restrict__ cursor,
                  int* __restrict__ bsum) {
    __shared__ int ws[4];
    __shared__ int tot;
    int t = threadIdx.x;
    int i = blockIdx.x * 256 + t;
    int x = (i < V) ? cnt[i] : 0;
    int ex = block_excl_scan(x, t, ws);
    if (i < V) cursor[i] = ex;
    if (t == 255) tot = ex + x;
    __syncthreads();
    if (t == 0) bsum[blockIdx.x] = tot;
}

// scatter + fused block-offset scan: writes sorted srcs/dsts/eidx
__global__ __launch_bounds__(256)
void scatter_kernel(const int* __restrict__ ei, int* __restrict__ cursor,
                    const int* __restrict__ bsum,
                    int* __restrict__ srcs, int* __restrict__ dsts,
                    int* __restrict__ eidx) {
    __shared__ int ws[4];
    __shared__ int sboff[NSCAN];
    int t = threadIdx.x;
    int x = (t < NSCAN) ? bsum[t] : 0;
    int ex = block_excl_scan(x, t, ws);
    if (t < NSCAN) sboff[t] = ex;
    __syncthreads();
    int e = blockIdx.x * 256 + t;                      // 3125*256 = E exact
    int d = ei[E_EDGES + e];
    int pos = atomicAdd(&cursor[d], 1) + sboff[d >> 8];
    srcs[pos] = ei[e];
    dsts[pos] = d;
    eidx[pos] = e;
}

// ---- edge MLP + segmented scatter (software-pipelined) ----------------
__global__ __launch_bounds__(256, 3)
void edge_kernel(const unsigned short* __restrict__ hbf,
                 const float* __restrict__ ea,
                 const int* __restrict__ srcs, const int* __restrict__ dsts,
                 const int* __restrict__ eidx,
                 const unsigned short* __restrict__ W1p, const unsigned short* __restrict__ W2p,
                 const float* __restrict__ b1, const float* __restrict__ b2,
                 float* __restrict__ agg) {
    union SharedU {
        struct { unsigned short Xs[64 * XSTR]; unsigned short Ys[64 * YSTR]; } s; // 38,912 B
        float C[64 * CSTR];                                                        // 33,792 B
    };
    __shared__ __align__(16) SharedU u;
    __shared__ int sDst[64];

    const int tid  = threadIdx.x;
    const int lane = tid & 63;
    const int wave = tid >> 6;      // owns N cols [wave*32, wave*32+32)
    const int nlo  = lane & 15;
    const int kq   = lane >> 4;
    const int er   = tid >> 4;      // gather row base 0..15 (+16*it)
    const int ec   = tid & 15;      // gather 16B chunk 0..15
    const int ee   = tid >> 2;      // ea row 0..63
    const int eq   = tid & 3;       // ea quad

    // Persistent B fragments
    bf16x8 B1[5][2], B2[4][2];
    float b1v[2], b2v[2];
    #pragma unroll
    for (int t = 0; t < 2; ++t) {
        int n = wave * 32 + t * 16 + nlo;
        b1v[t] = b1[n];
        b2v[t] = b2[n];
        #pragma unroll
        for (int kb = 0; kb < 5; ++kb)
            B1[kb][t] = *(const bf16x8*)(W1p + ((kb << 7) + n) * 32 + (kq << 3));
        #pragma unroll
        for (int kb = 0; kb < 4; ++kb)
            B2[kb][t] = *(const bf16x8*)(W2p + ((kb << 7) + n) * 32 + (kq << 3));
    }

    // ---- pipeline prologue: data for tile0 in pf regs, indices for tile0+G
    const int base0 = blockIdx.x << 6;
    int a0 = srcs[base0 + er];
    int a1 = srcs[base0 + er + 16];
    int a2 = srcs[base0 + er + 32];
    int a3 = srcs[base0 + er + 48];
    int aev = eidx[base0 + ee];
    int ddcur = dsts[base0 + lane];
    bf16x8 pf0 = *(const bf16x8*)(hbf + (size_t)a0 * D + (ec << 3));
    bf16x8 pf1 = *(const bf16x8*)(hbf + (size_t)a1 * D + (ec << 3));
    bf16x8 pf2 = *(const bf16x8*)(hbf + (size_t)a2 * D + (ec << 3));
    bf16x8 pf3 = *(const bf16x8*)(hbf + (size_t)a3 * D + (ec << 3));
    float4 pfe = *(const float4*)(ea + (size_t)aev * EF + (eq << 2));

    int n1 = blockIdx.x + EGRID;
    int nb1 = (n1 < NT ? n1 : blockIdx.x) << 6;
    int i1s0 = srcs[nb1 + er];
    int i1s1 = srcs[nb1 + er + 16];
    int i1s2 = srcs[nb1 + er + 32];
    int i1s3 = srcs[nb1 + er + 48];
    int i1e  = eidx[nb1 + ee];
    int i1d  = dsts[nb1 + lane];

    for (int tile = blockIdx.x; tile < NT; tile += EGRID) {
        // A: issue index loads for tile+2G
        int n2 = tile + 2 * EGRID;
        int nb2 = (n2 < NT ? n2 : tile) << 6;
        int i2s0 = srcs[nb2 + er];
        int i2s1 = srcs[nb2 + er + 16];
        int i2s2 = srcs[nb2 + er + 32];
        int i2s3 = srcs[nb2 + er + 48];
        int i2e  = eidx[nb2 + ee];
        int i2d  = dsts[nb2 + lane];

        // B: publish current tile (regs -> LDS)
        if (tid < 64) sDst[tid] = ddcur;
        *(bf16x8*)(u.s.Xs + er * XSTR + (ec << 3))        = pf0;
        *(bf16x8*)(u.s.Xs + (er + 16) * XSTR + (ec << 3)) = pf1;
        *(bf16x8*)(u.s.Xs + (er + 32) * XSTR + (ec << 3)) = pf2;
        *(bf16x8*)(u.s.Xs + (er + 48) * XSTR + (ec << 3)) = pf3;
        {
            unsigned* xp = (unsigned*)(u.s.Xs) + ee * (XSTR / 2) + 64 + (eq << 1);
            xp[0] = pack2(pfe.x, pfe.y);
            xp[1] = pack2(pfe.z, pfe.w);
        }
        {   // zero pad k = 144..159
            int i0 = tid, i1 = tid + 256;
            ((unsigned*)(u.s.Xs))[(i0 >> 3) * (XSTR / 2) + 72 + (i0 & 7)] = 0u;
            ((unsigned*)(u.s.Xs))[(i1 >> 3) * (XSTR / 2) + 72 + (i1 & 7)] = 0u;
        }
        __syncthreads();

        // C: issue data gathers for tile+G (consumed next iteration)
        bf16x8 q0 = *(const bf16x8*)(hbf + (size_t)i1s0 * D + (ec << 3));
        bf16x8 q1 = *(const bf16x8*)(hbf + (size_t)i1s1 * D + (ec << 3));
        bf16x8 q2 = *(const bf16x8*)(hbf + (size_t)i1s2 * D + (ec << 3));
        bf16x8 q3 = *(const bf16x8*)(hbf + (size_t)i1s3 * D + (ec << 3));
        float4 qe = *(const float4*)(ea + (size_t)i1e * EF + (eq << 2));
        int nextdd = i1d;

        // ---- Stage 1: X[64,160] @ W1 ----
        f32x4 acc[4][2];
        #pragma unroll
        for (int mt = 0; mt < 4; ++mt)
            #pragma unroll
            for (int t = 0; t < 2; ++t)
                acc[mt][t] = (f32x4){0.f, 0.f, 0.f, 0.f};

        #pragma unroll
        for (int kb = 0; kb < 5; ++kb) {
            bf16x8 A[4];
            int ko = kb * 32 + (kq << 3);
            #pragma unroll
            for (int mt = 0; mt < 4; ++mt)
                A[mt] = *(const bf16x8*)(u.s.Xs + (mt * 16 + nlo) * XSTR + ko);
            #pragma unroll
            for (int mt = 0; mt < 4; ++mt)
                #pragma unroll
                for (int t = 0; t < 2; ++t)
                    acc[mt][t] = __builtin_amdgcn_mfma_f32_16x16x32_bf16(A[mt], B1[kb][t], acc[mt][t], 0, 0, 0);
        }

        // bias + ReLU -> Ys (bf16)
        #pragma unroll
        for (int mt = 0; mt < 4; ++mt)
            #pragma unroll
            for (int t = 0; t < 2; ++t)
                #pragma unroll
                for (int r = 0; r < 4; ++r) {
                    float v = fmaxf(acc[mt][t][r] + b1v[t], 0.0f);
                    int row = mt * 16 + (kq << 2) + r;
                    int col = wave * 32 + t * 16 + nlo;
                    u.s.Ys[row * YSTR + col] = f2bf(v);
                }
        __syncthreads();

        // ---- Stage 2: Y[64,128] @ W2 ----
        f32x4 acc2[4][2];
        #pragma unroll
        for (int mt = 0; mt < 4; ++mt)
            #pragma unroll
            for (int t = 0; t < 2; ++t)
                acc2[mt][t] = (f32x4){0.f, 0.f, 0.f, 0.f};

        #pragma unroll
        for (int kb = 0; kb < 4; ++kb) {
            bf16x8 A[4];
            int ko = kb * 32 + (kq << 3);
            #pragma unroll
            for (int mt = 0; mt < 4; ++mt)
                A[mt] = *(const bf16x8*)(u.s.Ys + (mt * 16 + nlo) * YSTR + ko);
            #pragma unroll
            for (int mt = 0; mt < 4; ++mt)
                #pragma unroll
                for (int t = 0; t < 2; ++t)
                    acc2[mt][t] = __builtin_amdgcn_mfma_f32_16x16x32_bf16(A[mt], B2[kb][t], acc2[mt][t], 0, 0, 0);
        }
        __syncthreads();    // all Ys reads done before C overwrites the union

        // C = acc2 + b2 -> LDS (f32, [row][col])
        #pragma unroll
        for (int mt = 0; mt < 4; ++mt)
            #pragma unroll
            for (int t = 0; t < 2; ++t)
                #pragma unroll
                for (int r = 0; r < 4; ++r) {
                    int row = mt * 16 + (kq << 2) + r;
                    int col = wave * 32 + t * 16 + nlo;
                    u.C[row * CSTR + col] = acc2[mt][t][r] + b2v[t];
                }
        __syncthreads();

        // segmented run-reduction over sorted dst: ~1 atomic per (run, col)
        {
            int col = tid & 127;
            int rbase = (tid >> 7) << 5;            // rows [rbase, rbase+32)
            float sum = 0.f;
            int cur = sDst[rbase];
            for (int i = 0; i < 32; ++i) {
                int row = rbase + i;
                int d = sDst[row];                  // wave-uniform broadcast
                if (d != cur) {
                    atomicAdd(&agg[(size_t)cur * D + col], sum);
                    sum = 0.f;
                    cur = d;
                }
                sum += u.C[row * CSTR + col];
            }
            atomicAdd(&agg[(size_t)cur * D + col], sum);
        }
        __syncthreads();    // scans done before next tile's staging

        // rotate pipeline registers
        pf0 = q0; pf1 = q1; pf2 = q2; pf3 = q3; pfe = qe; ddcur = nextdd;
        i1s0 = i2s0; i1s1 = i2s1; i1s2 = i2s2; i1s3 = i2s3; i1e = i2e; i1d = i2d;
    }
}

// out = LayerNorm(h + agg/(1+deg)) * gamma + beta ; one wave per node
__global__ __launch_bounds__(256)
void finalize_kernel(const float* __restrict__ h, const float* __restrict__ agg,
                     const int* __restrict__ cnt,
                     const float* __restrict__ gamma, const float* __restrict__ beta,
                     float* __restrict__ out) {
    int wave = threadIdx.x >> 6, lane = threadIdx.x & 63;
    int v = blockIdx.x * 4 + wave;
    if (v >= V) return;
    float inv = 1.0f / (1.0f + (float)cnt[v]);
    const float* hr = h + (size_t)v * D;
    const float* ar = agg + (size_t)v * D;
    float x0 = hr[lane]      + ar[lane]      * inv;
    float x1 = hr[lane + 64] + ar[lane + 64] * inv;
    float s = x0 + x1;
    #pragma unroll
    for (int m = 32; m; m >>= 1) s += __shfl_xor(s, m);
    float mu = s * (1.0f / 128.0f);
    float d0 = x0 - mu, d1 = x1 - mu;
    float vs = d0 * d0 + d1 * d1;
    #pragma unroll
    for (int m = 32; m; m >>= 1) vs += __shfl_xor(vs, m);
    float rs = rsqrtf(vs * (1.0f / 128.0f) + 1e-5f);
    out[(size_t)v * D + lane]      = d0 * rs * gamma[lane]      + beta[lane];
    out[(size_t)v * D + 64 + lane] = d1 * rs * gamma[lane + 64] + beta[lane + 64];
}

extern "C" void kernel_launch(void* const* d_in, const int* in_sizes, int n_in,
                              void* d_out, int out_size, void* d_ws, size_t ws_size,
                              hipStream_t stream) {
    const float* h     = (const float*)d_in[0];
    const int*   ei    = (const int*)d_in[1];     // [2,E]: row0=src, row1=dst
    const float* ea    = (const float*)d_in[2];
    const float* W1    = (const float*)d_in[3];
    const float* b1    = (const float*)d_in[4];
    const float* W2    = (const float*)d_in[5];
    const float* b2    = (const float*)d_in[6];
    const float* gamma = (const float*)d_in[7];
    const float* beta  = (const float*)d_in[8];
    float* out = (float*)d_out;

    char* ws = (char*)d_ws;
    float*          agg    = (float*)ws;                          // 25,600,000
    int*            cnt    = (int*)(ws + 25600000);               //    200,000 (deg)
    int*            cursor = (int*)(ws + 25800000);               //    200,000
    int*            bsum   = (int*)(ws + 26000000);               //        800
    int*            srcs   = (int*)(ws + 26000800);               //  3,200,000
    int*            dsts   = (int*)(ws + 29200800);               //  3,200,000
    int*            eidx   = (int*)(ws + 32400800);               //  3,200,000
    unsigned short* W1p    = (unsigned short*)(ws + 35600800);    //     40,960
    unsigned short* W2p    = (unsigned short*)(ws + 35641760);    //     32,768
    unsigned short* hbf    = (unsigned short*)(ws + 35674528);    // 12,800,000 (~48.5 MB)

    hipMemsetAsync(cnt, 0, 200000, stream);
    setup_kernel<<<6250, 256, 0, stream>>>(h, hbf, ei, cnt, agg, W1, W2, W1p, W2p);
    scan1_kernel<<<NSCAN, 256, 0, stream>>>(cnt, cursor, bsum);
    scatter_kernel<<<3125, 256, 0, stream>>>(ei, cursor, bsum, srcs, dsts, eidx);
    edge_kernel<<<EGRID, 256, 0, stream>>>(hbf, ea, srcs, dsts, eidx, W1p, W2p, b1, b2, agg);
    finalize_kernel<<<12500, 256, 0, stream>>>(h, agg, cnt, gamma, beta, out);
}